// Round 16
// baseline (269.739 us; speedup 1.0000x reference)
//
#include <hip/hip_runtime.h>
#include <math.h>

// Problem constants
#define NN    6272     // tokens per batch = 8*28*28
#define NBAT  2
#define CCH   512      // in channels
#define HCH   256      // hidden channels
#define SPLIT 4        // kv-split factor (uniform 49-tile chunks) — SPLIT=8 regressed twice (r6, r12)

typedef float          f32x4  __attribute__((ext_vector_type(4)));
typedef float          f32x16 __attribute__((ext_vector_type(16)));
typedef unsigned int   u32x2  __attribute__((ext_vector_type(2)));
typedef unsigned int   u32x4  __attribute__((ext_vector_type(4)));
typedef _Float16       f16x8  __attribute__((ext_vector_type(8)));
typedef unsigned short u16x8  __attribute__((ext_vector_type(8)));
typedef unsigned short u16x4  __attribute__((ext_vector_type(4)));

// Scratch as device globals.
__device__ __attribute__((aligned(16))) unsigned short g_Xt[NBAT * NN * CCH]; // x^T [n][m][c] fp16
__device__ __attribute__((aligned(16))) unsigned short g_Wq[HCH * CCH];
__device__ __attribute__((aligned(16))) unsigned short g_Wk[HCH * CCH];
__device__ __attribute__((aligned(16))) unsigned short g_Wv[HCH * CCH];
__device__ __attribute__((aligned(16))) unsigned short g_Wo[CCH * HCH];
__device__ __attribute__((aligned(16))) unsigned short g_Qg[NBAT * NN * HCH]; // theta*16*log2e [n][m][o]
__device__ __attribute__((aligned(16))) unsigned short g_Kg[NBAT * NN * HCH]; // phi [n][kv][o], 16B o-chunk ^= kv&31
__device__ __attribute__((aligned(16))) unsigned short g_Vt[NBAT * HCH * NN]; // g^T [n][o][kv], 8-elem kv-chunk in 32-blk ^= (o>>3)&3
__device__ __attribute__((aligned(16))) unsigned short g_Yp[SPLIT * NBAT * HCH * NN]; // NORMALIZED partial y (f16) [s][n][o][m]
__device__ __attribute__((aligned(16))) float g_Mp[SPLIT * NBAT * NN];  // running max, LOG2 units
__device__ __attribute__((aligned(16))) float g_Lp[SPLIT * NBAT * NN];

static __device__ __forceinline__ unsigned short f2h(float f) {
  _Float16 h = (_Float16)f;
  return __builtin_bit_cast(unsigned short, h);
}
static __device__ __forceinline__ float h2f(unsigned short u) {
  return (float)__builtin_bit_cast(_Float16, u);
}
static __device__ __forceinline__ f16x8 ldf(const unsigned short* p) {
  return __builtin_bit_cast(f16x8, *(const u32x4*)p);
}
// single-instruction exp2 (hardware v_exp_f32; D = 2^S0)
static __device__ __forceinline__ float ex2(float x) {
  float r;
  asm("v_exp_f32 %0, %1" : "=v"(r) : "v"(x));
  return r;
}

#define GL16(g, l) __builtin_amdgcn_global_load_lds(                                   \
    (const __attribute__((address_space(1))) void*)(g),                                \
    (__attribute__((address_space(3))) void*)(l), 16, 0, 0)

// -------------------------------- fused prep: weight fp32->fp16 convert (blocks
// 0..511, float4 x 4 elems/thread) + x [n][c][m] -> Xt [n][m][c] fp16 transpose
// (blocks 512..2079). Independent producers — merged so they overlap on the CUs.
__global__ __launch_bounds__(256) void prep_kernel(const float* __restrict__ wt,
                                                   const float* __restrict__ wp,
                                                   const float* __restrict__ wg,
                                                   const float* __restrict__ wo,
                                                   const float* __restrict__ x) {
  __shared__ __attribute__((aligned(16))) unsigned short tile[64][72];
  const int bid = blockIdx.x;
  const int tid = threadIdx.x;
  if (bid < 512) {
    int off = (bid * 256 + tid) * 4;     // 0 .. 524284, within one 131072 segment
    int seg = off >> 17;
    int o   = off & 131071;
    const float* s = (seg == 0) ? wt : (seg == 1) ? wp : (seg == 2) ? wg : wo;
    unsigned short* d = (seg == 0) ? g_Wq : (seg == 1) ? g_Wk : (seg == 2) ? g_Wv : g_Wo;
    float4 v = *(const float4*)(s + o);
    u16x4 h;
    h[0] = f2h(v.x); h[1] = f2h(v.y); h[2] = f2h(v.z); h[3] = f2h(v.w);
    *(u16x4*)(d + o) = h;
  } else {
    const int b  = bid - 512;
    const int m0 = (b % 98) * 64;
    const int c0 = ((b / 98) & 7) * 64;
    const int nb = b / (98 * 8);
    const float* src = x + ((size_t)(nb * CCH + c0)) * NN + m0;
#pragma unroll
    for (int p = 0; p < 4; ++p) {
      int r  = p * 16 + (tid >> 4);
      int cc = (tid & 15) * 4;
      float4 v = *(const float4*)(src + (size_t)r * NN + cc);
      u16x4 h;
      h[0] = f2h(v.x); h[1] = f2h(v.y); h[2] = f2h(v.z); h[3] = f2h(v.w);
      *(u16x4*)&tile[r][cc] = h;
    }
    __syncthreads();
    unsigned short* dstbase = g_Xt + ((size_t)nb * NN + m0) * CCH + c0;
    const int m   = tid & 63;
    const int cgb = (tid >> 6) * 2;
#pragma unroll
    for (int p = 0; p < 2; ++p) {
      int cg = (cgb + p) * 8;
      u16x8 v;
#pragma unroll
      for (int j = 0; j < 8; ++j) v[j] = tile[cg + j][m];
      *(u16x8*)(dstbase + (size_t)m * CCH + cg) = v;
    }
  }
}

// -------------------------------- fused Q/K/V projections, z-merged (Xt tile read
// once per block instead of twice). Grid (98, NBAT, 3):
// z=0: Q (scaled 16*log2e) then K (16B o-chunk ^= kv&31), sequential passes;
// z=1: V o-tiles {0,64}; z=2: V o-tiles {128,192} (8-elem kv-chunk ^= (o>>3)&3).
__global__ __launch_bounds__(256) void proj_qkv_kernel() {
  const int tid  = threadIdx.x;
  const int lane = tid & 63;
  const int w    = tid >> 6;
  const int lo   = lane & 15, hi = lane >> 4;
  const int m0   = blockIdx.x * 64;
  const int nb   = blockIdx.y;
  const int z    = blockIdx.z;

  if (z == 0) {
    const unsigned short* xrow = g_Xt + ((size_t)nb * NN + m0 + w * 16 + lo) * CCH + hi * 8;
    size_t rowbase = (size_t)nb * NN + m0 + w * 16 + hi * 4;
#pragma unroll
    for (int which = 0; which < 2; ++which) {
      const unsigned short* W  = which ? g_Wk : g_Wq;
      unsigned short*      dst = which ? g_Kg : g_Qg;
      f32x4 acc[16];
#pragma unroll
      for (int i = 0; i < 16; ++i) acc[i] = (f32x4){0.f, 0.f, 0.f, 0.f};
      for (int ks = 0; ks < 16; ++ks) {
        f16x8 a = ldf(xrow + ks * 32);
#pragma unroll
        for (int of = 0; of < 16; ++of) {
          f16x8 b = ldf(W + (size_t)(of * 16 + lo) * CCH + ks * 32 + hi * 8);
          acc[of] = __builtin_amdgcn_mfma_f32_16x16x32_f16(a, b, acc[of], 0, 0, 0);
        }
      }
      if (which == 0) {
        unsigned short* drow = dst + rowbase * HCH + lo;
#pragma unroll
        for (int of = 0; of < 16; ++of)
#pragma unroll
          for (int r = 0; r < 4; ++r)
            drow[(size_t)r * HCH + of * 16] = f2h(acc[of][r] * 23.083120654223414f); // 16*log2(e)
      } else {
#pragma unroll
        for (int of = 0; of < 16; ++of)
#pragma unroll
          for (int r = 0; r < 4; ++r) {
            int kvr = (w * 16 + hi * 4 + r) & 31;    // kv & 31 (m0 is 64-aligned)
            int oc  = (of * 2 + (lo >> 3)) ^ kvr;    // permuted 16B-chunk index (32 chunks)
            dst[(rowbase + r) * HCH + (oc << 3) + (lo & 7)] = f2h(acc[of][r]);
          }
      }
    }
  } else {
#pragma unroll
    for (int pass = 0; pass < 2; ++pass) {
      const int o0 = ((z - 1) * 2 + pass) * 64;     // z=1: 0,64; z=2: 128,192
      const unsigned short* wrow = g_Wv + (size_t)(o0 + w * 16 + lo) * CCH + hi * 8;
      f32x4 acc[4];
#pragma unroll
      for (int i = 0; i < 4; ++i) acc[i] = (f32x4){0.f, 0.f, 0.f, 0.f};
      for (int ks = 0; ks < 16; ++ks) {
        f16x8 a = ldf(wrow + ks * 32);
#pragma unroll
        for (int mf = 0; mf < 4; ++mf) {
          f16x8 b = ldf(g_Xt + ((size_t)nb * NN + m0 + mf * 16 + lo) * CCH + ks * 32 + hi * 8);
          acc[mf] = __builtin_amdgcn_mfma_f32_16x16x32_f16(a, b, acc[mf], 0, 0, 0);
        }
      }
#pragma unroll
      for (int mf = 0; mf < 4; ++mf)
#pragma unroll
        for (int r = 0; r < 4; ++r) {
          int o  = o0 + w * 16 + hi * 4 + r;
          int kv = m0 + mf * 16 + lo;
          int c  = ((kv & 31) >> 3) ^ ((o >> 3) & 3);  // permuted 8-elem chunk in 32-blk
          int kvp = (kv & ~31) | (c << 3) | (kv & 7);
          g_Vt[((size_t)nb * HCH + o) * NN + kvp] = f2h(acc[mf][r]);
        }
    }
  }
}

// -------------------------------- attention: 32x32x16 MFMA, swapped QK^T,
// in-register log2-softmax (single v_exp_f32, permlane cross-half), PV lag-1
// pipeline, conflict-free swizzled K/V LDS, global_load_lds staging,
// ONE barrier + counted vmcnt(4) per iter, setprio around MFMA clusters.
// Grid 392: bid&7 -> (sp,nb) XCD-affine; bid>>3 -> m-tile of 128. 4 waves x 32 rows.
__global__ __launch_bounds__(256, 2) void attn_kernel() {
  __shared__ __attribute__((aligned(16))) unsigned short Kbuf[2][32 * 256];  // [kv][o] permuted
  __shared__ __attribute__((aligned(16))) unsigned short Vbuf[3][256 * 32];  // [o][kv] permuted

  const int tid  = threadIdx.x;
  const int wv   = tid >> 6;
  const int lane = tid & 63;
  const int lo5  = lane & 31, hi1 = lane >> 5;
  const int bid  = blockIdx.x;
  const int cmb  = bid & 7;
  const int sp   = cmb >> 1;
  const int nb   = cmb & 1;
  const int m0   = (bid >> 3) * 128;
  const int nts  = 49;
  const int kv0  = sp * (49 * 32);

  const unsigned short* Kb = g_Kg + (size_t)nb * NN * HCH;
  const unsigned short* Vb = g_Vt + (size_t)nb * HCH * NN;

  // Q B-frags: lane holds row m = m0+wv*32+lo5
  u32x4 qf[16];
  {
    const unsigned short* qrow = g_Qg + ((size_t)nb * NN + m0 + wv * 32 + lo5) * HCH + hi1 * 8;
#pragma unroll
    for (int t = 0; t < 16; ++t) qf[t] = *(const u32x4*)(qrow + t * 16);
  }

  f32x16 yacc[8];
#pragma unroll
  for (int i = 0; i < 8; ++i) yacc[i] = (f32x16)(0.f);
  float mrow = -3.0e38f, lrow = 0.f;   // mrow in LOG2 units
  u32x4 pfA[2];                 // P fragments of tile t-1 (consumed by PV next iter)
  pfA[0] = (u32x4)(0u); pfA[1] = (u32x4)(0u);

#define STAGE_K(buf, kvt)                                                               \
  {                                                                                     \
    const unsigned short* ks_ = Kb + (size_t)(kvt) * HCH + tid * 8;                     \
    unsigned short* kd_ = &Kbuf[buf][tid * 8];                                          \
    GL16(ks_,        kd_);                                                              \
    GL16(ks_ + 2048, kd_ + 2048);                                                       \
    GL16(ks_ + 4096, kd_ + 4096);                                                       \
    GL16(ks_ + 6144, kd_ + 6144);                                                       \
  }
#define STAGE_V(buf, kvt)                                                               \
  {                                                                                     \
    _Pragma("unroll")                                                                   \
    for (int p_ = 0; p_ < 4; ++p_) {                                                    \
      int idx_ = p_ * 256 + tid;                                                        \
      const unsigned short* vs_ = Vb + (size_t)(idx_ >> 2) * NN + (kvt) + (idx_ & 3) * 8; \
      GL16(vs_, &Vbuf[buf][idx_ * 8]);                                                  \
    }                                                                                   \
  }

  // prologue: stage tile 0
  STAGE_K(0, kv0);
  STAGE_V(0, kv0);

  int kc = 0;                         // Kbuf index holding K(t)
  int vprev = 2, vcur = 0, vnxt = 1;  // Vbuf rotation: V(t-1), V(t), V(t+1)

  for (int t = 0; t < nts; ++t) {
    // K(t), V(t-1) arrived; V(t) may still be in flight (newest 4 loads).
    asm volatile("s_waitcnt vmcnt(4) lgkmcnt(0)\n\ts_barrier" ::: "memory");
    if (t + 1 < nts) {
      const int kvn = kv0 + (t + 1) * 32;
      STAGE_K(kc ^ 1, kvn);
      STAGE_V(vnxt, kvn);
    }
    const unsigned short* Kl = &Kbuf[kc][0];
    const unsigned short* Vl = &Vbuf[vprev][0];
    // ---- S^T[kv][m] = K Q^T (16 MFMA, two chains explicitly interleaved)
    __builtin_amdgcn_s_setprio(1);
    f32x16 Sa = (f32x16)(0.f), Sb = (f32x16)(0.f);
#pragma unroll
    for (int tt = 0; tt < 8; ++tt) {
      f16x8 ka = ldf(Kl + lo5 * 256 + (((tt * 32 + hi1 * 16) ^ (lo5 << 4)) >> 1));
      f16x8 kb = ldf(Kl + lo5 * 256 + ((((tt + 8) * 32 + hi1 * 16) ^ (lo5 << 4)) >> 1));
      Sa = __builtin_amdgcn_mfma_f32_32x32x16_f16(ka, __builtin_bit_cast(f16x8, qf[tt]), Sa, 0, 0, 0);
      Sb = __builtin_amdgcn_mfma_f32_32x32x16_f16(kb, __builtin_bit_cast(f16x8, qf[tt + 8]), Sb, 0, 0, 0);
    }
    // ---- PV(t-1): 16 MFMAs; softmax VALU below overlaps them
    if (t > 0) {
#pragma unroll
      for (int of = 0; of < 8; ++of) {
#pragma unroll
        for (int s = 0; s < 2; ++s) {
          f16x8 va = ldf(Vl + (of * 32 + lo5) * 32 + (((s * 32 + hi1 * 16) ^ ((lo5 >> 3) << 4)) >> 1));
          yacc[of] = __builtin_amdgcn_mfma_f32_32x32x16_f16(va, __builtin_bit_cast(f16x8, pfA[s]), yacc[of], 0, 0, 0);
        }
      }
    }
    __builtin_amdgcn_s_setprio(0);
    // ---- online softmax(t) in log2 units (defer-max THR=11); tree max,
    //      cross-half exchange via permlane32_swap (VALU pipe, no lgkm)
    f32x16 S = Sa + Sb;
    float a0 = fmaxf(S[0], S[1]),   a1 = fmaxf(S[2], S[3]);
    float a2 = fmaxf(S[4], S[5]),   a3 = fmaxf(S[6], S[7]);
    float a4 = fmaxf(S[8], S[9]),   a5 = fmaxf(S[10], S[11]);
    float a6 = fmaxf(S[12], S[13]), a7 = fmaxf(S[14], S[15]);
    float b0 = fmaxf(a0, a1), b1 = fmaxf(a2, a3), b2 = fmaxf(a4, a5), b3 = fmaxf(a6, a7);
    float mx = fmaxf(fmaxf(b0, b1), fmaxf(b2, b3));
    {
      unsigned um = __builtin_bit_cast(unsigned, mx);
      u32x2 rm = __builtin_amdgcn_permlane32_swap(um, um, false, false);
      mx = fmaxf(mx, __builtin_bit_cast(float, hi1 ? rm[0] : rm[1]));
    }
    if (!__all(mx <= mrow + 11.0f)) {
      float mnew = fmaxf(mrow, mx);
      float fac  = ex2(mrow - mnew);
      mrow = mnew;
      lrow *= fac;
#pragma unroll
      for (int of = 0; of < 8; ++of) yacc[of] *= fac;   // rare (defer-max)
    }
    float p[16];
#pragma unroll
    for (int i = 0; i < 16; ++i) p[i] = ex2(S[i] - mrow);
    float rs = ((p[0] + p[1]) + (p[2] + p[3])) + ((p[4] + p[5]) + (p[6] + p[7]))
             + ((p[8] + p[9]) + (p[10] + p[11])) + ((p[12] + p[13]) + (p[14] + p[15]));
    {
      unsigned ur = __builtin_bit_cast(unsigned, rs);
      u32x2 rr = __builtin_amdgcn_permlane32_swap(ur, ur, false, false);
      rs += __builtin_bit_cast(float, hi1 ? rr[0] : rr[1]);
    }
    lrow += rs;
    // ---- pack P(t) -> B-frags: ONE permlane32_swap yields both halves
#pragma unroll
    for (int s = 0; s < 2; ++s) {
      unsigned int A0 = (unsigned int)f2h(p[8 * s + 0]) | ((unsigned int)f2h(p[8 * s + 1]) << 16);
      unsigned int A1 = (unsigned int)f2h(p[8 * s + 2]) | ((unsigned int)f2h(p[8 * s + 3]) << 16);
      unsigned int B0 = (unsigned int)f2h(p[8 * s + 4]) | ((unsigned int)f2h(p[8 * s + 5]) << 16);
      unsigned int B1 = (unsigned int)f2h(p[8 * s + 6]) | ((unsigned int)f2h(p[8 * s + 7]) << 16);
      u32x2 r0 = __builtin_amdgcn_permlane32_swap(A0, B0, false, false);
      u32x2 r1 = __builtin_amdgcn_permlane32_swap(A1, B1, false, false);
      pfA[s][0] = r0[0];
      pfA[s][1] = r1[0];
      pfA[s][2] = r0[1];
      pfA[s][3] = r1[1];
    }
    // rotate buffers
    kc ^= 1;
    vprev = vcur; vcur = vnxt; vnxt = (vnxt + 1 == 3) ? 0 : vnxt + 1;
  }
#undef STAGE_K
#undef STAGE_V
  // final PV(nts-1)
  asm volatile("s_waitcnt vmcnt(0) lgkmcnt(0)\n\ts_barrier" ::: "memory");
  {
    const unsigned short* Vl = &Vbuf[vprev][0];
#pragma unroll
    for (int of = 0; of < 8; ++of) {
#pragma unroll
      for (int s = 0; s < 2; ++s) {
        f16x8 va = ldf(Vl + (of * 32 + lo5) * 32 + (((s * 32 + hi1 * 16) ^ ((lo5 >> 3) << 4)) >> 1));
        yacc[of] = __builtin_amdgcn_mfma_f32_32x32x16_f16(va, __builtin_bit_cast(f16x8, pfA[s]), yacc[of], 0, 0, 0);
      }
    }
  }
  // epilogue: NORMALIZED partial y (f16) + m (log2 units), l per q-row
  {
    const int m = m0 + wv * 32 + lo5;
    const float inv = 1.0f / lrow;
    unsigned short* Yp = g_Yp + ((size_t)(sp * NBAT + nb) * HCH) * NN;
#pragma unroll
    for (int of = 0; of < 8; ++of)
#pragma unroll
      for (int reg = 0; reg < 16; ++reg) {
        int o = of * 32 + (reg & 3) + 8 * (reg >> 2) + 4 * hi1;
        Yp[(size_t)o * NN + m] = f2h(yacc[of][reg] * inv);
      }
    if (hi1 == 0) {
      size_t base = (size_t)(sp * NBAT + nb) * NN + m;
      g_Mp[base] = mrow;
      g_Lp[base] = lrow;
    }
  }
}

// -------------------------------- fused combine + output projection + residual.
// Grid (196, NBAT): block owns m-tile of 32, ALL o (256) and ALL c (512).
__global__ __launch_bounds__(256) void combout_kernel(const float* __restrict__ x,
                                                      float* __restrict__ out) {
  __shared__ __attribute__((aligned(16))) unsigned short Ylds[32][264];
  __shared__ float wls[SPLIT][32];
  const int tid = threadIdx.x;
  const int m0  = blockIdx.x * 32;
  const int nb  = blockIdx.y;
  // ---- phase 1: combine weights, log2 units
  if (tid < 32) {
    int m = m0 + tid;
    float ms[SPLIT], ls[SPLIT];
#pragma unroll
    for (int s = 0; s < SPLIT; ++s) {
      size_t idx = (size_t)(s * NBAT + nb) * NN + m;
      ms[s] = g_Mp[idx];
      ls[s] = g_Lp[idx];
    }
    float M = ms[0];
#pragma unroll
    for (int s = 1; s < SPLIT; ++s) M = fmaxf(M, ms[s]);
    float L = 0.f, w[SPLIT];
#pragma unroll
    for (int s = 0; s < SPLIT; ++s) { w[s] = ex2(ms[s] - M) * ls[s]; L += w[s]; }
    float inv = 1.0f / L;
#pragma unroll
    for (int s = 0; s < SPLIT; ++s) wls[s][tid] = w[s] * inv;
  }
  __syncthreads();
  // ---- phase 2: combine Yp (f16, [o][m]) -> Ylds[m][o]
  {
    const int mc = (tid & 1) * 16;       // m-chunk 0 / 16
    const int ob = tid >> 1;             // 0..127
#pragma unroll
    for (int oh = 0; oh < 2; ++oh) {
      const int o = oh * 128 + ob;
      float a[16];
#pragma unroll
      for (int j = 0; j < 16; ++j) a[j] = 0.f;
#pragma unroll
      for (int s = 0; s < SPLIT; ++s) {
        const unsigned short* src = g_Yp + ((size_t)(s * NBAT + nb) * HCH + o) * NN + m0 + mc;
        u16x8 v0 = *(const u16x8*)src;
        u16x8 v1 = *(const u16x8*)(src + 8);
#pragma unroll
        for (int j = 0; j < 8; ++j) a[j] += wls[s][mc + j] * h2f(v0[j]);
#pragma unroll
        for (int j = 0; j < 8; ++j) a[8 + j] += wls[s][mc + 8 + j] * h2f(v1[j]);
      }
#pragma unroll
      for (int j = 0; j < 16; ++j) Ylds[mc + j][o] = f2h(a[j]);
    }
  }
  __syncthreads();
  // ---- phase 3: out = x + Wo . y^T, 8 passes over c-tiles of 64
  const int lane = tid & 63;
  const int wv   = tid >> 6;
  const int lo   = lane & 15, hi = lane >> 4;
#pragma unroll
  for (int pass = 0; pass < 8; ++pass) {
    const int c0 = pass * 64;
    const unsigned short* wrow = g_Wo + (size_t)(c0 + wv * 16 + lo) * HCH + hi * 8;
    f32x4 acc0 = (f32x4){0.f, 0.f, 0.f, 0.f};
    f32x4 acc1 = (f32x4){0.f, 0.f, 0.f, 0.f};
#pragma unroll
    for (int ks = 0; ks < 8; ++ks) {
      f16x8 a  = ldf(wrow + ks * 32);
      f16x8 b0 = ldf(&Ylds[lo][ks * 32 + hi * 8]);
      f16x8 b1 = ldf(&Ylds[16 + lo][ks * 32 + hi * 8]);
      acc0 = __builtin_amdgcn_mfma_f32_16x16x32_f16(a, b0, acc0, 0, 0, 0);
      acc1 = __builtin_amdgcn_mfma_f32_16x16x32_f16(a, b1, acc1, 0, 0, 0);
    }
#pragma unroll
    for (int r = 0; r < 4; ++r) {
      size_t row  = (size_t)(nb * CCH + c0 + wv * 16 + hi * 4 + r);
      size_t idx0 = row * NN + m0 + lo;
      out[idx0]      = x[idx0]      + acc0[r];
      out[idx0 + 16] = x[idx0 + 16] + acc1[r];
    }
  }
}

extern "C" void kernel_launch(void* const* d_in, const int* in_sizes, int n_in,
                              void* d_out, int out_size, void* d_ws, size_t ws_size,
                              hipStream_t stream) {
  const float* x  = (const float*)d_in[0];
  const float* wg = (const float*)d_in[1];  // V weight
  const float* wt = (const float*)d_in[2];  // Q weight (theta)
  const float* wp = (const float*)d_in[3];  // K weight (phi)
  const float* wo = (const float*)d_in[4];  // out weight
  float* out = (float*)d_out;
  (void)in_sizes; (void)n_in; (void)d_ws; (void)ws_size; (void)out_size;

  prep_kernel<<<2080, 256, 0, stream>>>(wt, wp, wg, wo, x);
  proj_qkv_kernel<<<dim3(98, NBAT, 3), 256, 0, stream>>>();
  attn_kernel<<<392, 256, 0, stream>>>();
  combout_kernel<<<dim3(196, NBAT), 256, 0, stream>>>(x, out);
}

// Round 17
// 253.553 us; speedup vs baseline: 1.0638x; 1.0638x over previous
//
#include <hip/hip_runtime.h>
#include <math.h>

// Problem constants
#define NN    6272     // tokens per batch = 8*28*28
#define NBAT  2
#define CCH   512      // in channels
#define HCH   256      // hidden channels
#define SPLIT 4        // kv-split factor (uniform 49-tile chunks) — SPLIT=8 regressed twice (r6, r12)

typedef float          f32x4  __attribute__((ext_vector_type(4)));
typedef float          f32x16 __attribute__((ext_vector_type(16)));
typedef unsigned int   u32x2  __attribute__((ext_vector_type(2)));
typedef unsigned int   u32x4  __attribute__((ext_vector_type(4)));
typedef _Float16       f16x8  __attribute__((ext_vector_type(8)));
typedef unsigned short u16x8  __attribute__((ext_vector_type(8)));
typedef unsigned short u16x4  __attribute__((ext_vector_type(4)));

// Scratch as device globals.
__device__ __attribute__((aligned(16))) unsigned short g_Xt[NBAT * NN * CCH]; // x^T [n][m][c] fp16
__device__ __attribute__((aligned(16))) unsigned short g_Wq[HCH * CCH];
__device__ __attribute__((aligned(16))) unsigned short g_Wk[HCH * CCH];
__device__ __attribute__((aligned(16))) unsigned short g_Wv[HCH * CCH];
__device__ __attribute__((aligned(16))) unsigned short g_Wo[CCH * HCH];
__device__ __attribute__((aligned(16))) unsigned short g_Qg[NBAT * NN * HCH]; // theta*16*log2e [n][m][o]
__device__ __attribute__((aligned(16))) unsigned short g_Kg[NBAT * NN * HCH]; // phi [n][kv][o], 16B o-chunk ^= kv&31
__device__ __attribute__((aligned(16))) unsigned short g_Vt[NBAT * HCH * NN]; // g^T [n][o][kv], 8-elem kv-chunk in 32-blk ^= (o>>3)&3
__device__ __attribute__((aligned(16))) unsigned short g_Yp[SPLIT * NBAT * HCH * NN]; // NORMALIZED partial y (f16) [s][n][o][m]
__device__ __attribute__((aligned(16))) float g_Mp[SPLIT * NBAT * NN];  // running max, LOG2 units
__device__ __attribute__((aligned(16))) float g_Lp[SPLIT * NBAT * NN];

static __device__ __forceinline__ unsigned short f2h(float f) {
  _Float16 h = (_Float16)f;
  return __builtin_bit_cast(unsigned short, h);
}
static __device__ __forceinline__ float h2f(unsigned short u) {
  return (float)__builtin_bit_cast(_Float16, u);
}
static __device__ __forceinline__ f16x8 ldf(const unsigned short* p) {
  return __builtin_bit_cast(f16x8, *(const u32x4*)p);
}
// single-instruction exp2 (hardware v_exp_f32; D = 2^S0)
static __device__ __forceinline__ float ex2(float x) {
  float r;
  asm("v_exp_f32 %0, %1" : "=v"(r) : "v"(x));
  return r;
}

#define GL16(g, l) __builtin_amdgcn_global_load_lds(                                   \
    (const __attribute__((address_space(1))) void*)(g),                                \
    (__attribute__((address_space(3))) void*)(l), 16, 0, 0)

// -------------------------------- fused prep: weight fp32->fp16 convert (blocks
// 0..511, float4 x 4 elems/thread) + x [n][c][m] -> Xt [n][m][c] fp16 transpose
// (blocks 512..2079). Independent producers — merged so they overlap on the CUs.
__global__ __launch_bounds__(256) void prep_kernel(const float* __restrict__ wt,
                                                   const float* __restrict__ wp,
                                                   const float* __restrict__ wg,
                                                   const float* __restrict__ wo,
                                                   const float* __restrict__ x) {
  __shared__ __attribute__((aligned(16))) unsigned short tile[64][72];
  const int bid = blockIdx.x;
  const int tid = threadIdx.x;
  if (bid < 512) {
    int off = (bid * 256 + tid) * 4;     // 0 .. 524284, within one 131072 segment
    int seg = off >> 17;
    int o   = off & 131071;
    const float* s = (seg == 0) ? wt : (seg == 1) ? wp : (seg == 2) ? wg : wo;
    unsigned short* d = (seg == 0) ? g_Wq : (seg == 1) ? g_Wk : (seg == 2) ? g_Wv : g_Wo;
    float4 v = *(const float4*)(s + o);
    u16x4 h;
    h[0] = f2h(v.x); h[1] = f2h(v.y); h[2] = f2h(v.z); h[3] = f2h(v.w);
    *(u16x4*)(d + o) = h;
  } else {
    const int b  = bid - 512;
    const int m0 = (b % 98) * 64;
    const int c0 = ((b / 98) & 7) * 64;
    const int nb = b / (98 * 8);
    const float* src = x + ((size_t)(nb * CCH + c0)) * NN + m0;
#pragma unroll
    for (int p = 0; p < 4; ++p) {
      int r  = p * 16 + (tid >> 4);
      int cc = (tid & 15) * 4;
      float4 v = *(const float4*)(src + (size_t)r * NN + cc);
      u16x4 h;
      h[0] = f2h(v.x); h[1] = f2h(v.y); h[2] = f2h(v.z); h[3] = f2h(v.w);
      *(u16x4*)&tile[r][cc] = h;
    }
    __syncthreads();
    unsigned short* dstbase = g_Xt + ((size_t)nb * NN + m0) * CCH + c0;
    const int m   = tid & 63;
    const int cgb = (tid >> 6) * 2;
#pragma unroll
    for (int p = 0; p < 2; ++p) {
      int cg = (cgb + p) * 8;
      u16x8 v;
#pragma unroll
      for (int j = 0; j < 8; ++j) v[j] = tile[cg + j][m];
      *(u16x8*)(dstbase + (size_t)m * CCH + cg) = v;
    }
  }
}

// -------------------------------- fused Q/K/V projections (z slowest — benched fastest).
// z=0: Q scaled by 16*log2e (folds sqrt(d) + exp2 conversion); z=1: K (16B o-chunk
// ^= kv&31); z=2..5: V tile o0=(z-2)*64 (8-elem kv-chunk in 32-blk ^= (o>>3)&3).
__global__ __launch_bounds__(256) void proj_qkv_kernel() {
  const int tid  = threadIdx.x;
  const int lane = tid & 63;
  const int w    = tid >> 6;
  const int lo   = lane & 15, hi = lane >> 4;
  const int m0   = blockIdx.x * 64;
  const int nb   = blockIdx.y;
  const int z    = blockIdx.z;

  if (z < 2) {
    const unsigned short* W  = z ? g_Wk : g_Wq;
    unsigned short*      dst = z ? g_Kg : g_Qg;
    const unsigned short* xrow = g_Xt + ((size_t)nb * NN + m0 + w * 16 + lo) * CCH + hi * 8;
    f32x4 acc[16];
#pragma unroll
    for (int i = 0; i < 16; ++i) acc[i] = (f32x4){0.f, 0.f, 0.f, 0.f};
    for (int ks = 0; ks < 16; ++ks) {
      f16x8 a = ldf(xrow + ks * 32);
#pragma unroll
      for (int of = 0; of < 16; ++of) {
        f16x8 b = ldf(W + (size_t)(of * 16 + lo) * CCH + ks * 32 + hi * 8);
        acc[of] = __builtin_amdgcn_mfma_f32_16x16x32_f16(a, b, acc[of], 0, 0, 0);
      }
    }
    size_t rowbase = (size_t)nb * NN + m0 + w * 16 + hi * 4;
    if (z == 0) {
      unsigned short* drow = dst + rowbase * HCH + lo;
#pragma unroll
      for (int of = 0; of < 16; ++of)
#pragma unroll
        for (int r = 0; r < 4; ++r)
          drow[(size_t)r * HCH + of * 16] = f2h(acc[of][r] * 23.083120654223414f); // 16*log2(e)
    } else {
#pragma unroll
      for (int of = 0; of < 16; ++of)
#pragma unroll
        for (int r = 0; r < 4; ++r) {
          int kvr = (w * 16 + hi * 4 + r) & 31;    // kv & 31 (m0 is 64-aligned)
          int oc  = (of * 2 + (lo >> 3)) ^ kvr;    // permuted 16B-chunk index (32 chunks)
          dst[(rowbase + r) * HCH + (oc << 3) + (lo & 7)] = f2h(acc[of][r]);
        }
    }
  } else {
    const int o0 = (z - 2) * 64;
    const unsigned short* wrow = g_Wv + (size_t)(o0 + w * 16 + lo) * CCH + hi * 8;
    f32x4 acc[4];
#pragma unroll
    for (int i = 0; i < 4; ++i) acc[i] = (f32x4){0.f, 0.f, 0.f, 0.f};
    for (int ks = 0; ks < 16; ++ks) {
      f16x8 a = ldf(wrow + ks * 32);
#pragma unroll
      for (int mf = 0; mf < 4; ++mf) {
        f16x8 b = ldf(g_Xt + ((size_t)nb * NN + m0 + mf * 16 + lo) * CCH + ks * 32 + hi * 8);
        acc[mf] = __builtin_amdgcn_mfma_f32_16x16x32_f16(a, b, acc[mf], 0, 0, 0);
      }
    }
#pragma unroll
    for (int mf = 0; mf < 4; ++mf)
#pragma unroll
      for (int r = 0; r < 4; ++r) {
        int o  = o0 + w * 16 + hi * 4 + r;
        int kv = m0 + mf * 16 + lo;
        int c  = ((kv & 31) >> 3) ^ ((o >> 3) & 3);  // permuted 8-elem chunk in 32-blk
        int kvp = (kv & ~31) | (c << 3) | (kv & 7);
        g_Vt[((size_t)nb * HCH + o) * NN + kvp] = f2h(acc[mf][r]);
      }
  }
}

// -------------------------------- attention: 32x32x16 MFMA, swapped QK^T,
// in-register log2-softmax (single v_exp_f32, permlane cross-half), PV lag-1
// pipeline, conflict-free swizzled K/V LDS, global_load_lds staging,
// ONE barrier + counted vmcnt(4) per iter, setprio around MFMA clusters.
// Grid 392: bid&7 -> (sp,nb) XCD-affine; bid>>3 -> m-tile of 128. 4 waves x 32 rows.
__global__ __launch_bounds__(256, 2) void attn_kernel() {
  __shared__ __attribute__((aligned(16))) unsigned short Kbuf[2][32 * 256];  // [kv][o] permuted
  __shared__ __attribute__((aligned(16))) unsigned short Vbuf[3][256 * 32];  // [o][kv] permuted

  const int tid  = threadIdx.x;
  const int wv   = tid >> 6;
  const int lane = tid & 63;
  const int lo5  = lane & 31, hi1 = lane >> 5;
  const int bid  = blockIdx.x;
  const int cmb  = bid & 7;
  const int sp   = cmb >> 1;
  const int nb   = cmb & 1;
  const int m0   = (bid >> 3) * 128;
  const int nts  = 49;
  const int kv0  = sp * (49 * 32);

  const unsigned short* Kb = g_Kg + (size_t)nb * NN * HCH;
  const unsigned short* Vb = g_Vt + (size_t)nb * HCH * NN;

  // Q B-frags: lane holds row m = m0+wv*32+lo5
  u32x4 qf[16];
  {
    const unsigned short* qrow = g_Qg + ((size_t)nb * NN + m0 + wv * 32 + lo5) * HCH + hi1 * 8;
#pragma unroll
    for (int t = 0; t < 16; ++t) qf[t] = *(const u32x4*)(qrow + t * 16);
  }

  f32x16 yacc[8];
#pragma unroll
  for (int i = 0; i < 8; ++i) yacc[i] = (f32x16)(0.f);
  float mrow = -3.0e38f, lrow = 0.f;   // mrow in LOG2 units
  u32x4 pfA[2];                 // P fragments of tile t-1 (consumed by PV next iter)
  pfA[0] = (u32x4)(0u); pfA[1] = (u32x4)(0u);

#define STAGE_K(buf, kvt)                                                               \
  {                                                                                     \
    const unsigned short* ks_ = Kb + (size_t)(kvt) * HCH + tid * 8;                     \
    unsigned short* kd_ = &Kbuf[buf][tid * 8];                                          \
    GL16(ks_,        kd_);                                                              \
    GL16(ks_ + 2048, kd_ + 2048);                                                       \
    GL16(ks_ + 4096, kd_ + 4096);                                                       \
    GL16(ks_ + 6144, kd_ + 6144);                                                       \
  }
#define STAGE_V(buf, kvt)                                                               \
  {                                                                                     \
    _Pragma("unroll")                                                                   \
    for (int p_ = 0; p_ < 4; ++p_) {                                                    \
      int idx_ = p_ * 256 + tid;                                                        \
      const unsigned short* vs_ = Vb + (size_t)(idx_ >> 2) * NN + (kvt) + (idx_ & 3) * 8; \
      GL16(vs_, &Vbuf[buf][idx_ * 8]);                                                  \
    }                                                                                   \
  }

  // prologue: stage tile 0
  STAGE_K(0, kv0);
  STAGE_V(0, kv0);

  int kc = 0;                         // Kbuf index holding K(t)
  int vprev = 2, vcur = 0, vnxt = 1;  // Vbuf rotation: V(t-1), V(t), V(t+1)

  for (int t = 0; t < nts; ++t) {
    // K(t), V(t-1) arrived; V(t) may still be in flight (newest 4 loads).
    asm volatile("s_waitcnt vmcnt(4) lgkmcnt(0)\n\ts_barrier" ::: "memory");
    if (t + 1 < nts) {
      const int kvn = kv0 + (t + 1) * 32;
      STAGE_K(kc ^ 1, kvn);
      STAGE_V(vnxt, kvn);
    }
    const unsigned short* Kl = &Kbuf[kc][0];
    const unsigned short* Vl = &Vbuf[vprev][0];
    // ---- S^T[kv][m] = K Q^T (16 MFMA, two chains explicitly interleaved)
    __builtin_amdgcn_s_setprio(1);
    f32x16 Sa = (f32x16)(0.f), Sb = (f32x16)(0.f);
#pragma unroll
    for (int tt = 0; tt < 8; ++tt) {
      f16x8 ka = ldf(Kl + lo5 * 256 + (((tt * 32 + hi1 * 16) ^ (lo5 << 4)) >> 1));
      f16x8 kb = ldf(Kl + lo5 * 256 + ((((tt + 8) * 32 + hi1 * 16) ^ (lo5 << 4)) >> 1));
      Sa = __builtin_amdgcn_mfma_f32_32x32x16_f16(ka, __builtin_bit_cast(f16x8, qf[tt]), Sa, 0, 0, 0);
      Sb = __builtin_amdgcn_mfma_f32_32x32x16_f16(kb, __builtin_bit_cast(f16x8, qf[tt + 8]), Sb, 0, 0, 0);
    }
    // ---- PV(t-1): 16 MFMAs; softmax VALU below overlaps them
    if (t > 0) {
#pragma unroll
      for (int of = 0; of < 8; ++of) {
#pragma unroll
        for (int s = 0; s < 2; ++s) {
          f16x8 va = ldf(Vl + (of * 32 + lo5) * 32 + (((s * 32 + hi1 * 16) ^ ((lo5 >> 3) << 4)) >> 1));
          yacc[of] = __builtin_amdgcn_mfma_f32_32x32x16_f16(va, __builtin_bit_cast(f16x8, pfA[s]), yacc[of], 0, 0, 0);
        }
      }
    }
    __builtin_amdgcn_s_setprio(0);
    // ---- online softmax(t) in log2 units (defer-max THR=11); tree max,
    //      cross-half exchange via permlane32_swap (VALU pipe, no lgkm)
    f32x16 S = Sa + Sb;
    float a0 = fmaxf(S[0], S[1]),   a1 = fmaxf(S[2], S[3]);
    float a2 = fmaxf(S[4], S[5]),   a3 = fmaxf(S[6], S[7]);
    float a4 = fmaxf(S[8], S[9]),   a5 = fmaxf(S[10], S[11]);
    float a6 = fmaxf(S[12], S[13]), a7 = fmaxf(S[14], S[15]);
    float b0 = fmaxf(a0, a1), b1 = fmaxf(a2, a3), b2 = fmaxf(a4, a5), b3 = fmaxf(a6, a7);
    float mx = fmaxf(fmaxf(b0, b1), fmaxf(b2, b3));
    {
      unsigned um = __builtin_bit_cast(unsigned, mx);
      u32x2 rm = __builtin_amdgcn_permlane32_swap(um, um, false, false);
      mx = fmaxf(mx, __builtin_bit_cast(float, hi1 ? rm[0] : rm[1]));
    }
    if (!__all(mx <= mrow + 11.0f)) {
      float mnew = fmaxf(mrow, mx);
      float fac  = ex2(mrow - mnew);
      mrow = mnew;
      lrow *= fac;
#pragma unroll
      for (int of = 0; of < 8; ++of) yacc[of] *= fac;   // rare (defer-max)
    }
    float p[16];
#pragma unroll
    for (int i = 0; i < 16; ++i) p[i] = ex2(S[i] - mrow);
    float rs = ((p[0] + p[1]) + (p[2] + p[3])) + ((p[4] + p[5]) + (p[6] + p[7]))
             + ((p[8] + p[9]) + (p[10] + p[11])) + ((p[12] + p[13]) + (p[14] + p[15]));
    {
      unsigned ur = __builtin_bit_cast(unsigned, rs);
      u32x2 rr = __builtin_amdgcn_permlane32_swap(ur, ur, false, false);
      rs += __builtin_bit_cast(float, hi1 ? rr[0] : rr[1]);
    }
    lrow += rs;
    // ---- pack P(t) -> B-frags: ONE permlane32_swap yields both halves
#pragma unroll
    for (int s = 0; s < 2; ++s) {
      unsigned int A0 = (unsigned int)f2h(p[8 * s + 0]) | ((unsigned int)f2h(p[8 * s + 1]) << 16);
      unsigned int A1 = (unsigned int)f2h(p[8 * s + 2]) | ((unsigned int)f2h(p[8 * s + 3]) << 16);
      unsigned int B0 = (unsigned int)f2h(p[8 * s + 4]) | ((unsigned int)f2h(p[8 * s + 5]) << 16);
      unsigned int B1 = (unsigned int)f2h(p[8 * s + 6]) | ((unsigned int)f2h(p[8 * s + 7]) << 16);
      u32x2 r0 = __builtin_amdgcn_permlane32_swap(A0, B0, false, false);
      u32x2 r1 = __builtin_amdgcn_permlane32_swap(A1, B1, false, false);
      pfA[s][0] = r0[0];
      pfA[s][1] = r1[0];
      pfA[s][2] = r0[1];
      pfA[s][3] = r1[1];
    }
    // rotate buffers
    kc ^= 1;
    vprev = vcur; vcur = vnxt; vnxt = (vnxt + 1 == 3) ? 0 : vnxt + 1;
  }
#undef STAGE_K
#undef STAGE_V
  // final PV(nts-1)
  asm volatile("s_waitcnt vmcnt(0) lgkmcnt(0)\n\ts_barrier" ::: "memory");
  {
    const unsigned short* Vl = &Vbuf[vprev][0];
#pragma unroll
    for (int of = 0; of < 8; ++of) {
#pragma unroll
      for (int s = 0; s < 2; ++s) {
        f16x8 va = ldf(Vl + (of * 32 + lo5) * 32 + (((s * 32 + hi1 * 16) ^ ((lo5 >> 3) << 4)) >> 1));
        yacc[of] = __builtin_amdgcn_mfma_f32_32x32x16_f16(va, __builtin_bit_cast(f16x8, pfA[s]), yacc[of], 0, 0, 0);
      }
    }
  }
  // epilogue: NORMALIZED partial y (f16) + m (log2 units), l per q-row
  {
    const int m = m0 + wv * 32 + lo5;
    const float inv = 1.0f / lrow;
    unsigned short* Yp = g_Yp + ((size_t)(sp * NBAT + nb) * HCH) * NN;
#pragma unroll
    for (int of = 0; of < 8; ++of)
#pragma unroll
      for (int reg = 0; reg < 16; ++reg) {
        int o = of * 32 + (reg & 3) + 8 * (reg >> 2) + 4 * hi1;
        Yp[(size_t)o * NN + m] = f2h(yacc[of][reg] * inv);
      }
    if (hi1 == 0) {
      size_t base = (size_t)(sp * NBAT + nb) * NN + m;
      g_Mp[base] = mrow;
      g_Lp[base] = lrow;
    }
  }
}

// -------------------------------- fused combine + output projection + residual.
// Grid (196, NBAT): block owns m-tile of 32, ALL o (256) and ALL c (512).
__global__ __launch_bounds__(256) void combout_kernel(const float* __restrict__ x,
                                                      float* __restrict__ out) {
  __shared__ __attribute__((aligned(16))) unsigned short Ylds[32][264];
  __shared__ float wls[SPLIT][32];
  const int tid = threadIdx.x;
  const int m0  = blockIdx.x * 32;
  const int nb  = blockIdx.y;
  // ---- phase 1: combine weights, log2 units
  if (tid < 32) {
    int m = m0 + tid;
    float ms[SPLIT], ls[SPLIT];
#pragma unroll
    for (int s = 0; s < SPLIT; ++s) {
      size_t idx = (size_t)(s * NBAT + nb) * NN + m;
      ms[s] = g_Mp[idx];
      ls[s] = g_Lp[idx];
    }
    float M = ms[0];
#pragma unroll
    for (int s = 1; s < SPLIT; ++s) M = fmaxf(M, ms[s]);
    float L = 0.f, w[SPLIT];
#pragma unroll
    for (int s = 0; s < SPLIT; ++s) { w[s] = ex2(ms[s] - M) * ls[s]; L += w[s]; }
    float inv = 1.0f / L;
#pragma unroll
    for (int s = 0; s < SPLIT; ++s) wls[s][tid] = w[s] * inv;
  }
  __syncthreads();
  // ---- phase 2: combine Yp (f16, [o][m]) -> Ylds[m][o]
  {
    const int mc = (tid & 1) * 16;       // m-chunk 0 / 16
    const int ob = tid >> 1;             // 0..127
#pragma unroll
    for (int oh = 0; oh < 2; ++oh) {
      const int o = oh * 128 + ob;
      float a[16];
#pragma unroll
      for (int j = 0; j < 16; ++j) a[j] = 0.f;
#pragma unroll
      for (int s = 0; s < SPLIT; ++s) {
        const unsigned short* src = g_Yp + ((size_t)(s * NBAT + nb) * HCH + o) * NN + m0 + mc;
        u16x8 v0 = *(const u16x8*)src;
        u16x8 v1 = *(const u16x8*)(src + 8);
#pragma unroll
        for (int j = 0; j < 8; ++j) a[j] += wls[s][mc + j] * h2f(v0[j]);
#pragma unroll
        for (int j = 0; j < 8; ++j) a[8 + j] += wls[s][mc + 8 + j] * h2f(v1[j]);
      }
#pragma unroll
      for (int j = 0; j < 16; ++j) Ylds[mc + j][o] = f2h(a[j]);
    }
  }
  __syncthreads();
  // ---- phase 3: out = x + Wo . y^T, 8 passes over c-tiles of 64
  const int lane = tid & 63;
  const int wv   = tid >> 6;
  const int lo   = lane & 15, hi = lane >> 4;
#pragma unroll
  for (int pass = 0; pass < 8; ++pass) {
    const int c0 = pass * 64;
    const unsigned short* wrow = g_Wo + (size_t)(c0 + wv * 16 + lo) * HCH + hi * 8;
    f32x4 acc0 = (f32x4){0.f, 0.f, 0.f, 0.f};
    f32x4 acc1 = (f32x4){0.f, 0.f, 0.f, 0.f};
#pragma unroll
    for (int ks = 0; ks < 8; ++ks) {
      f16x8 a  = ldf(wrow + ks * 32);
      f16x8 b0 = ldf(&Ylds[lo][ks * 32 + hi * 8]);
      f16x8 b1 = ldf(&Ylds[16 + lo][ks * 32 + hi * 8]);
      acc0 = __builtin_amdgcn_mfma_f32_16x16x32_f16(a, b0, acc0, 0, 0, 0);
      acc1 = __builtin_amdgcn_mfma_f32_16x16x32_f16(a, b1, acc1, 0, 0, 0);
    }
#pragma unroll
    for (int r = 0; r < 4; ++r) {
      size_t row  = (size_t)(nb * CCH + c0 + wv * 16 + hi * 4 + r);
      size_t idx0 = row * NN + m0 + lo;
      out[idx0]      = x[idx0]      + acc0[r];
      out[idx0 + 16] = x[idx0 + 16] + acc1[r];
    }
  }
}

extern "C" void kernel_launch(void* const* d_in, const int* in_sizes, int n_in,
                              void* d_out, int out_size, void* d_ws, size_t ws_size,
                              hipStream_t stream) {
  const float* x  = (const float*)d_in[0];
  const float* wg = (const float*)d_in[1];  // V weight
  const float* wt = (const float*)d_in[2];  // Q weight (theta)
  const float* wp = (const float*)d_in[3];  // K weight (phi)
  const float* wo = (const float*)d_in[4];  // out weight
  float* out = (float*)d_out;
  (void)in_sizes; (void)n_in; (void)d_ws; (void)ws_size; (void)out_size;

  prep_kernel<<<2080, 256, 0, stream>>>(wt, wp, wg, wo, x);
  proj_qkv_kernel<<<dim3(98, NBAT, 6), 256, 0, stream>>>();
  attn_kernel<<<392, 256, 0, stream>>>();
  combout_kernel<<<dim3(196, NBAT), 256, 0, stream>>>(x, out);
}